// Round 4
// baseline (120.863 us; speedup 1.0000x reference)
//
#include <hip/hip_runtime.h>
#include <hip/hip_bf16.h>

#define LOG2E 1.4426950408889634f

typedef __attribute__((ext_vector_type(8))) short bf16x8;
typedef __attribute__((ext_vector_type(4))) float f32x4;
typedef __attribute__((ext_vector_type(16))) float f32x16;

__device__ __forceinline__ short f2bf(float a) {
  __hip_bfloat16 h = __float2bfloat16(a);
  return *reinterpret_cast<short*>(&h);
}
__device__ __forceinline__ unsigned pkbf(float a, float b) {
  return (unsigned)(unsigned short)f2bf(a) | ((unsigned)(unsigned short)f2bf(b) << 16);
}
__device__ __forceinline__ unsigned cvtpk(float a, float b) {
  unsigned r;
  asm("v_cvt_pk_bf16_f32 %0, %1, %2" : "=v"(r) : "v"(a), "v"(b));
  return r;
}
__device__ __forceinline__ float extlo(unsigned u) {
  unsigned v = u << 16; float f; __builtin_memcpy(&f, &v, 4); return f;
}
__device__ __forceinline__ float exthi(unsigned u) {
  unsigned v = u & 0xffff0000u; float f; __builtin_memcpy(&f, &v, 4); return f;
}
union FragU8 { unsigned d[4]; bf16x8 v; };

// ---------------- Kernel 0: transpose-convert ----------------
__global__ __launch_bounds__(256) void haloattn_cvt(
    const float* __restrict__ x, const float* __restrict__ q_w,
    const float* __restrict__ kv_w, unsigned short* __restrict__ xT,
    unsigned short* __restrict__ w_bf)
{
  __shared__ float Ld[64][68];
  const int t = threadIdx.x;
  const int pt = blockIdx.x, kt = blockIdx.y, b = blockIdx.z;
  {
    const int flat = ((b << 2) + kt) * 64 + pt;
    const int idx = flat * 64 + (t & 63);
    if (t < 64) {
      const float wv = (idx < 32768) ? q_w[idx] : kv_w[idx - 32768];
      w_bf[idx] = (unsigned short)f2bf(wv);
    }
  }
  const float* xb = x + ((size_t)b * 256 + (kt << 6)) * 4096 + (pt << 6);
#pragma unroll
  for (int ps = 0; ps < 4; ++ps) {
    const int kloc = (ps << 4) + (t >> 4);
    const int ploc = (t & 15) << 2;
    float4 v = *(const float4*)(xb + (size_t)kloc * 4096 + ploc);
    *(float4*)&Ld[kloc][ploc] = v;
  }
  __syncthreads();
  const int pl = t >> 2;
  const int ks = (t & 3) << 4;
  float f[16];
#pragma unroll
  for (int i = 0; i < 16; ++i) f[i] = Ld[ks + i][pl];
  uint4 o0, o1;
  o0.x = pkbf(f[0], f[1]);   o0.y = pkbf(f[2], f[3]);
  o0.z = pkbf(f[4], f[5]);   o0.w = pkbf(f[6], f[7]);
  o1.x = pkbf(f[8], f[9]);   o1.y = pkbf(f[10], f[11]);
  o1.z = pkbf(f[12], f[13]); o1.w = pkbf(f[14], f[15]);
  unsigned short* op = xT + ((size_t)(b << 12) + (pt << 6) + pl) * 256 + (kt << 6) + ks;
  *(uint4*)op = o0;
  *(uint4*)(op + 8) = o1;
}

// ---------------- Kernel 1: fused q/kv projection (bf16 MFMA) ----------------
__global__ __launch_bounds__(512, 4) void haloattn_proj_mfma(
    const unsigned short* __restrict__ xT, const unsigned short* __restrict__ w_bf,
    unsigned short* __restrict__ q_bf, unsigned short* __restrict__ kv_bf)
{
  __shared__ unsigned short Wt[256][68];
  __shared__ unsigned short Xt[128][68];
  const int tid = threadIdx.x;
  const int w = tid >> 6, l = tid & 63;
  const int b = blockIdx.z, oBase = blockIdx.y << 8, pBase = blockIdx.x << 7;
  const int wm = w >> 1, wn = w & 1;
  const int g = l >> 4, c = l & 15;

  f32x4 acc[4][4] = {};

  const int srow = tid >> 3;
  const int se3  = (tid & 7) << 3;

  for (int chk = 0; chk < 4; ++chk) {
    const int k0 = chk << 6;
#pragma unroll
    for (int ps = 0; ps < 4; ++ps) {
      const int row = (ps << 6) + srow;
      uint4 wv = *(const uint4*)(w_bf + (size_t)(oBase + row) * 256 + k0 + se3);
      char* dst = (char*)&Wt[0][0] + row * 136 + (se3 << 1);
      *(uint2*)dst = make_uint2(wv.x, wv.y);
      *(uint2*)(dst + 8) = make_uint2(wv.z, wv.w);
    }
#pragma unroll
    for (int ps = 0; ps < 2; ++ps) {
      const int p = (ps << 6) + srow;
      uint4 xv = *(const uint4*)(xT + ((size_t)(b << 12) + pBase + p) * 256 + k0 + se3);
      char* dst = (char*)&Xt[0][0] + p * 136 + (se3 << 1);
      *(uint2*)dst = make_uint2(xv.x, xv.y);
      *(uint2*)(dst + 8) = make_uint2(xv.z, xv.w);
    }
    __syncthreads();
#pragma unroll
    for (int kk = 0; kk < 2; ++kk) {
      FragU8 bfr[4];
#pragma unroll
      for (int nf = 0; nf < 4; ++nf) {
        const char* src = (const char*)&Xt[0][0]
            + ((wn << 6) + (nf << 4) + c) * 136 + (kk << 6) + (g << 4);
        uint2 lo = *(const uint2*)src, hi2 = *(const uint2*)(src + 8);
        bfr[nf].d[0] = lo.x; bfr[nf].d[1] = lo.y;
        bfr[nf].d[2] = hi2.x; bfr[nf].d[3] = hi2.y;
      }
#pragma unroll
      for (int mf = 0; mf < 4; ++mf) {
        const char* src = (const char*)&Wt[0][0]
            + ((wm << 6) + (mf << 4) + c) * 136 + (kk << 6) + (g << 4);
        uint2 lo = *(const uint2*)src, hi2 = *(const uint2*)(src + 8);
        FragU8 af;
        af.d[0] = lo.x; af.d[1] = lo.y; af.d[2] = hi2.x; af.d[3] = hi2.y;
#pragma unroll
        for (int nf = 0; nf < 4; ++nf)
          acc[mf][nf] = __builtin_amdgcn_mfma_f32_16x16x32_bf16(af.v, bfr[nf].v, acc[mf][nf], 0, 0, 0);
      }
    }
    __syncthreads();
  }
#pragma unroll
  for (int mf = 0; mf < 4; ++mf) {
    const int o = oBase + (wm << 6) + (mf << 4) + (g << 2);
#pragma unroll
    for (int nf = 0; nf < 4; ++nf) {
      const int p = pBase + (wn << 6) + (nf << 4) + c;
      uint2 pk2 = make_uint2(pkbf(acc[mf][nf][0], acc[mf][nf][1]),
                             pkbf(acc[mf][nf][2], acc[mf][nf][3]));
      if (o < 128) {
        const int head = o >> 4;
        const int z = (b << 3) + head;
        const int y = p >> 6, xx = p & 63;
        const int nbb = ((y >> 3) << 3) + (xx >> 3);
        const int qi = ((y & 7) << 3) + (xx & 7);
        *(uint2*)(q_bf + (((size_t)z * 64 + nbb) * 64 + qi) * 16 + (o & 15)) = pk2;
      } else {
        *(uint2*)(kv_bf + ((size_t)(b << 12) + p) * 384 + (o - 128)) = pk2;
      }
    }
  }
}

// ---------------- Kernel 2: halo attention, 32x32 MFMA, no-max softmax ----------------
// 1 wave per (z, nb). Chunk = 2 window rows x 16 slots (j 0..13 valid).
// S^T = K*Q^T + pos-embed (tables in regs); p = exp2(s); out^T = V^T * P^T.
__global__ __launch_bounds__(64, 3) void haloattn_attn_mfma32(
    const unsigned short* __restrict__ q_bf, const unsigned short* __restrict__ kv_bf,
    const float* __restrict__ height_rel, const float* __restrict__ width_rel,
    float* __restrict__ out)
{
  __shared__ __align__(16) unsigned char lds[10656];
  unsigned short* HRs = (unsigned short*)lds;            // [32][24] bf16 (prologue)
  unsigned short* WRs = (unsigned short*)(lds + 1536);   // [32][24] bf16 (prologue)
  float* Htmp = (float*)(lds + 3072);                    // [27][35] f32 (prologue)
  float* Wtmp = (float*)(lds + 6852);                    // [27][35] f32 (prologue)
  unsigned char* Kb = lds;                               // [32][24] bf16 (main)
  unsigned char* Vb = lds + 1536;                        // [32][40] bf16 (main, V^T)

  const int l = threadIdx.x;
  const int q32 = l & 31;
  const int hi = l >> 5;
  const int nb = blockIdx.x, z = blockIdx.y;
  const int b = z >> 3, head = z & 7;
  const int bi = nb >> 3, bj = nb & 7;
  const int swapA = (l ^ 32) << 2;
  const f32x16 z16 = {};
  const float qs = 0.25f * LOG2E;

  // ---- Q fragments (B-operand): col=q32, k = 8*hi + j ----
  const unsigned short* qtile = q_bf + ((size_t)z * 64 + nb) * 1024;
  bf16x8 qfrag[2];
  qfrag[0] = *(const bf16x8*)(qtile + q32 * 16 + 8 * hi);
  qfrag[1] = *(const bf16x8*)(qtile + (32 + q32) * 16 + 8 * hi);

  // ---- stage rel tables (bf16, xLOG2E) ----
  if (l < 54) {
    const int u = l >> 1, d0 = (l & 1) << 3;
    float4 a = *(const float4*)(height_rel + u * 16 + d0);
    float4 b4 = *(const float4*)(height_rel + u * 16 + d0 + 4);
    uint4 o;
    o.x = cvtpk(a.x * LOG2E, a.y * LOG2E);
    o.y = cvtpk(a.z * LOG2E, a.w * LOG2E);
    o.z = cvtpk(b4.x * LOG2E, b4.y * LOG2E);
    o.w = cvtpk(b4.z * LOG2E, b4.w * LOG2E);
    *(uint4*)(HRs + u * 24 + d0) = o;
    a = *(const float4*)(width_rel + u * 16 + d0);
    b4 = *(const float4*)(width_rel + u * 16 + d0 + 4);
    o.x = cvtpk(a.x * LOG2E, a.y * LOG2E);
    o.y = cvtpk(a.z * LOG2E, a.w * LOG2E);
    o.z = cvtpk(b4.x * LOG2E, b4.y * LOG2E);
    o.w = cvtpk(b4.z * LOG2E, b4.w * LOG2E);
    *(uint4*)(WRs + u * 24 + d0) = o;
  } else {
    const int t = l - 54;
    const int u = 27 + (t >> 1), d0 = (t & 1) << 3;
    uint4 o = {};
    *(uint4*)(HRs + u * 24 + d0) = o;
    *(uint4*)(WRs + u * 24 + d0) = o;
  }
  __syncthreads();

  // ---- bias tables via MFMA: C[u][q] = sum_d REL[u][d] * Q[q][d] ----
  bf16x8 hfr = *(const bf16x8*)((const unsigned char*)HRs + q32 * 48 + 16 * hi);
  bf16x8 wfr = *(const bf16x8*)((const unsigned char*)WRs + q32 * 48 + 16 * hi);

  unsigned hpk[2][7];
  unsigned wpk[2][8];
#pragma unroll
  for (int nt = 0; nt < 2; ++nt) {
    f32x16 Ch = __builtin_amdgcn_mfma_f32_32x32x16_bf16(hfr, qfrag[nt], z16, 0, 0, 0);
    f32x16 Cw = __builtin_amdgcn_mfma_f32_32x32x16_bf16(wfr, qfrag[nt], z16, 0, 0, 0);
    __syncthreads();
#pragma unroll
    for (int r = 0; r < 16; ++r) {
      const int u = (r & 3) + 8 * (r >> 2) + 4 * hi;
      if (u < 27) {
        Htmp[u * 35 + q32] = Ch[r];
        Wtmp[u * 35 + q32] = Cw[r];
      }
    }
    __syncthreads();
    const int qfull = nt * 32 + q32;
    const int qh = qfull >> 3, qw = q32 & 7;
    const float* hb = Htmp + (13 - qh) * 35 + q32;
    const float* wb = Wtmp + (13 - qw) * 35 + q32;
#pragma unroll
    for (int cc = 0; cc < 7; ++cc)
      hpk[nt][cc] = cvtpk(hb[(2 * cc) * 35], hb[(2 * cc + 1) * 35]);
#pragma unroll
    for (int tt = 0; tt < 7; ++tt)
      wpk[nt][tt] = cvtpk(wb[(2 * tt) * 35], wb[(2 * tt + 1) * 35]);
    wpk[nt][7] = 0u;
  }
  __syncthreads();

  // ---- staging precompute ----
  const int jj = q32 & 15;          // slot j
  const int ir = q32 >> 4;          // slot row parity
  const int xx = bj * 8 + jj - 3;
  const int yyb = bi * 8 + ir - 3;
  const bool xval = (jj < 14) && ((unsigned)xx < 64u);
  const unsigned short* kvbase = kv_bf + (size_t)b * 4096 * 384 + head * 48;

  f32x16 acc[2] = {};
  float lrow[2] = {0.f, 0.f};

#pragma unroll
  for (int c = 0; c < 7; ++c) {
    // ---- stage K (b128) + V^T (scalar scatter) ----
    {
      const int yy = yyb + 2 * c;
      const bool val = xval && ((unsigned)yy < 64u);
      const unsigned short* rp = kvbase + (size_t)((yy << 6) + xx) * 384;
      uint4 k4 = {}, va = {}, vb2 = {};
      if (val) {
        k4  = *(const uint4*)(rp + 8 * hi);
        va  = *(const uint4*)(rp + 16 + 16 * hi);
        vb2 = *(const uint4*)(rp + 16 + 16 * hi + 8);
      }
      *(uint4*)(Kb + q32 * 48 + 16 * hi) = k4;
      const unsigned short* sa = (const unsigned short*)&va;
      const unsigned short* sb = (const unsigned short*)&vb2;
      unsigned short* vt = (unsigned short*)Vb;
#pragma unroll
      for (int t = 0; t < 8; ++t) vt[(16 * hi + t) * 40 + q32] = sa[t];
#pragma unroll
      for (int t = 0; t < 8; ++t) vt[(16 * hi + 8 + t) * 40 + q32] = sb[t];
    }
    __syncthreads();

    bf16x8 kf  = *(const bf16x8*)(Kb + q32 * 48 + 16 * hi);
    bf16x8 vf0 = *(const bf16x8*)(Vb + q32 * 80 + 16 * hi);
    bf16x8 vf1 = *(const bf16x8*)(Vb + q32 * 80 + 32 + 16 * hi);

#pragma unroll
    for (int nt = 0; nt < 2; ++nt) {
      f32x16 Cs = __builtin_amdgcn_mfma_f32_32x32x16_bf16(kf, qfrag[nt], z16, 0, 0, 0);
      const float hA = extlo(hpk[nt][c]);
      const float hB = exthi(hpk[nt][c]);
      const unsigned wd0 = hi ? wpk[nt][2] : wpk[nt][0];
      const unsigned wd1 = hi ? wpk[nt][3] : wpk[nt][1];
      const unsigned wd4 = hi ? wpk[nt][6] : wpk[nt][4];
      const unsigned wd5 = hi ? wpk[nt][7] : wpk[nt][5];
      float p[16];
#pragma unroll
      for (int r = 0; r < 16; ++r) {
        const int kjb = (r & 3) + 8 * ((r >> 2) & 1);
        const unsigned wdw = (kjb < 4) ? ((kjb < 2) ? wd0 : wd1)
                                       : (((kjb & 3) < 2) ? wd4 : wd5);
        const float wv = (kjb & 1) ? exthi(wdw) : extlo(wdw);
        const float h = (r < 8) ? hA : hB;
        float s = fmaf(Cs[r], qs, h + wv);
        if (r == 6 || r == 7 || r == 14 || r == 15)
          s = hi ? -1e30f : s;
        p[r] = exp2f(s);
      }
      // l accumulation (tree)
      {
        float s0 = (p[0] + p[1]) + (p[2] + p[3]);
        float s1 = (p[4] + p[5]) + (p[6] + p[7]);
        float s2 = (p[8] + p[9]) + (p[10] + p[11]);
        float s3 = (p[12] + p[13]) + (p[14] + p[15]);
        lrow[nt] += (s0 + s1) + (s2 + s3);
      }
      // ---- repack P -> B fragments (2 k-slices) ----
      unsigned dw[8], xw[8];
#pragma unroll
      for (int k = 0; k < 8; ++k) dw[k] = cvtpk(p[2 * k], p[2 * k + 1]);
#pragma unroll
      for (int k = 0; k < 8; ++k)
        xw[k] = (unsigned)__builtin_amdgcn_ds_bpermute(swapA, (int)dw[k]);
      FragU8 f0, f1;
      f0.d[0] = hi ? xw[2] : dw[0];
      f0.d[1] = hi ? xw[3] : dw[1];
      f0.d[2] = hi ? dw[2] : xw[0];
      f0.d[3] = hi ? dw[3] : xw[1];
      f1.d[0] = hi ? xw[6] : dw[4];
      f1.d[1] = hi ? xw[7] : dw[5];
      f1.d[2] = hi ? dw[6] : xw[4];
      f1.d[3] = hi ? dw[7] : xw[5];
      acc[nt] = __builtin_amdgcn_mfma_f32_32x32x16_bf16(vf0, f0.v, acc[nt], 0, 0, 0);
      acc[nt] = __builtin_amdgcn_mfma_f32_32x32x16_bf16(vf1, f1.v, acc[nt], 0, 0, 0);
    }
    __syncthreads();
  }

  // ---- epilogue ----
#pragma unroll
  for (int nt = 0; nt < 2; ++nt) {
    const float L = lrow[nt] + __shfl_xor(lrow[nt], 32);
    const float invL = 1.f / L;
    const int qt = nt * 32 + q32;
    const int yq = bi * 8 + (qt >> 3);
    const int xq = bj * 8 + (q32 & 7);
    float* obase = out + ((size_t)(b * 256 + head * 32) * 4096) + yq * 64 + xq;
#pragma unroll
    for (int r = 0; r < 16; ++r) {
      const int d = (r & 3) + 8 * (r >> 2) + 4 * hi;
      obase[(size_t)d * 4096] = acc[nt][r] * invL;
    }
  }
}

extern "C" void kernel_launch(void* const* d_in, const int* in_sizes, int n_in,
                              void* d_out, int out_size, void* d_ws, size_t ws_size,
                              hipStream_t stream) {
  const float* x          = (const float*)d_in[0];
  const float* q_w        = (const float*)d_in[1];
  const float* kv_w       = (const float*)d_in[2];
  const float* height_rel = (const float*)d_in[3];
  const float* width_rel  = (const float*)d_in[4];
  float* out = (float*)d_out;

  unsigned short* q_bf  = (unsigned short*)d_ws;          // 4,194,304
  unsigned short* kv_bf = q_bf + (size_t)4194304;         // 12,582,912
  unsigned short* xT    = kv_bf + (size_t)12582912;       // 8,388,608
  unsigned short* w_bf  = xT + (size_t)8388608;           // 131,072

  haloattn_cvt<<<dim3(64, 4, 8), 256, 0, stream>>>(x, q_w, kv_w, xT, w_bf);
  haloattn_proj_mfma<<<dim3(32, 2, 8), 512, 0, stream>>>(xT, w_bf, q_bf, kv_bf);
  haloattn_attn_mfma32<<<dim3(64, 64), 64, 0, stream>>>(q_bf, kv_bf, height_rel, width_rel, out);
}

// Round 5
// 100.997 us; speedup vs baseline: 1.1967x; 1.1967x over previous
//
#include <hip/hip_runtime.h>
#include <hip/hip_bf16.h>

#define LOG2E 1.4426950408889634f

typedef __attribute__((ext_vector_type(8))) short bf16x8;
typedef __attribute__((ext_vector_type(4))) float f32x4;
typedef __attribute__((ext_vector_type(16))) float f32x16;

__device__ __forceinline__ short f2bf(float a) {
  __hip_bfloat16 h = __float2bfloat16(a);
  return *reinterpret_cast<short*>(&h);
}
__device__ __forceinline__ unsigned pkbf(float a, float b) {
  return (unsigned)(unsigned short)f2bf(a) | ((unsigned)(unsigned short)f2bf(b) << 16);
}
__device__ __forceinline__ unsigned cvtpk(float a, float b) {
  unsigned r;
  asm("v_cvt_pk_bf16_f32 %0, %1, %2" : "=v"(r) : "v"(a), "v"(b));
  return r;
}
__device__ __forceinline__ float bfu2f(unsigned u16v) {
  unsigned v = u16v << 16; float f; __builtin_memcpy(&f, &v, 4); return f;
}
union FragU8 { unsigned d[4]; bf16x8 v; };
union KU { uint4 u; bf16x8 v; };

// ---------------- Kernel 0: transpose-convert ----------------
__global__ __launch_bounds__(256) void haloattn_cvt(
    const float* __restrict__ x, const float* __restrict__ q_w,
    const float* __restrict__ kv_w, unsigned short* __restrict__ xT,
    unsigned short* __restrict__ w_bf)
{
  __shared__ float Ld[64][68];
  const int t = threadIdx.x;
  const int pt = blockIdx.x, kt = blockIdx.y, b = blockIdx.z;
  {
    const int flat = ((b << 2) + kt) * 64 + pt;
    const int idx = flat * 64 + (t & 63);
    if (t < 64) {
      const float wv = (idx < 32768) ? q_w[idx] : kv_w[idx - 32768];
      w_bf[idx] = (unsigned short)f2bf(wv);
    }
  }
  const float* xb = x + ((size_t)b * 256 + (kt << 6)) * 4096 + (pt << 6);
#pragma unroll
  for (int ps = 0; ps < 4; ++ps) {
    const int kloc = (ps << 4) + (t >> 4);
    const int ploc = (t & 15) << 2;
    float4 v = *(const float4*)(xb + (size_t)kloc * 4096 + ploc);
    *(float4*)&Ld[kloc][ploc] = v;
  }
  __syncthreads();
  const int pl = t >> 2;
  const int ks = (t & 3) << 4;
  float f[16];
#pragma unroll
  for (int i = 0; i < 16; ++i) f[i] = Ld[ks + i][pl];
  uint4 o0, o1;
  o0.x = pkbf(f[0], f[1]);   o0.y = pkbf(f[2], f[3]);
  o0.z = pkbf(f[4], f[5]);   o0.w = pkbf(f[6], f[7]);
  o1.x = pkbf(f[8], f[9]);   o1.y = pkbf(f[10], f[11]);
  o1.z = pkbf(f[12], f[13]); o1.w = pkbf(f[14], f[15]);
  unsigned short* op = xT + ((size_t)(b << 12) + (pt << 6) + pl) * 256 + (kt << 6) + ks;
  *(uint4*)op = o0;
  *(uint4*)(op + 8) = o1;
}

// ---------------- Kernel 1: fused q/kv projection (bf16 MFMA) ----------------
// q -> (z, nb, qi, d) bf16; K -> [b][head][pix][16] bf16; V -> padded planes
// [b][head][d=32][70][72] bf16 (interior written here, borders pre-zeroed).
__global__ __launch_bounds__(512, 4) void haloattn_proj_mfma(
    const unsigned short* __restrict__ xT, const unsigned short* __restrict__ w_bf,
    unsigned short* __restrict__ q_bf, unsigned short* __restrict__ kbuf,
    unsigned short* __restrict__ vpln)
{
  __shared__ unsigned short Wt[256][68];
  __shared__ unsigned short Xt[128][68];
  const int tid = threadIdx.x;
  const int w = tid >> 6, l = tid & 63;
  const int b = blockIdx.z, oBase = blockIdx.y << 8, pBase = blockIdx.x << 7;
  const int wm = w >> 1, wn = w & 1;
  const int g = l >> 4, c = l & 15;

  f32x4 acc[4][4] = {};

  const int srow = tid >> 3;
  const int se3  = (tid & 7) << 3;

  for (int chk = 0; chk < 4; ++chk) {
    const int k0 = chk << 6;
#pragma unroll
    for (int ps = 0; ps < 4; ++ps) {
      const int row = (ps << 6) + srow;
      uint4 wv = *(const uint4*)(w_bf + (size_t)(oBase + row) * 256 + k0 + se3);
      char* dst = (char*)&Wt[0][0] + row * 136 + (se3 << 1);
      *(uint2*)dst = make_uint2(wv.x, wv.y);
      *(uint2*)(dst + 8) = make_uint2(wv.z, wv.w);
    }
#pragma unroll
    for (int ps = 0; ps < 2; ++ps) {
      const int p = (ps << 6) + srow;
      uint4 xv = *(const uint4*)(xT + ((size_t)(b << 12) + pBase + p) * 256 + k0 + se3);
      char* dst = (char*)&Xt[0][0] + p * 136 + (se3 << 1);
      *(uint2*)dst = make_uint2(xv.x, xv.y);
      *(uint2*)(dst + 8) = make_uint2(xv.z, xv.w);
    }
    __syncthreads();
#pragma unroll
    for (int kk = 0; kk < 2; ++kk) {
      FragU8 bfr[4];
#pragma unroll
      for (int nf = 0; nf < 4; ++nf) {
        const char* src = (const char*)&Xt[0][0]
            + ((wn << 6) + (nf << 4) + c) * 136 + (kk << 6) + (g << 4);
        uint2 lo = *(const uint2*)src, hi2 = *(const uint2*)(src + 8);
        bfr[nf].d[0] = lo.x; bfr[nf].d[1] = lo.y;
        bfr[nf].d[2] = hi2.x; bfr[nf].d[3] = hi2.y;
      }
#pragma unroll
      for (int mf = 0; mf < 4; ++mf) {
        const char* src = (const char*)&Wt[0][0]
            + ((wm << 6) + (mf << 4) + c) * 136 + (kk << 6) + (g << 4);
        uint2 lo = *(const uint2*)src, hi2 = *(const uint2*)(src + 8);
        FragU8 af;
        af.d[0] = lo.x; af.d[1] = lo.y; af.d[2] = hi2.x; af.d[3] = hi2.y;
#pragma unroll
        for (int nf = 0; nf < 4; ++nf)
          acc[mf][nf] = __builtin_amdgcn_mfma_f32_16x16x32_bf16(af.v, bfr[nf].v, acc[mf][nf], 0, 0, 0);
      }
    }
    __syncthreads();
  }
#pragma unroll
  for (int mf = 0; mf < 4; ++mf) {
    const int o = oBase + (wm << 6) + (mf << 4) + (g << 2);
#pragma unroll
    for (int nf = 0; nf < 4; ++nf) {
      const int p = pBase + (wn << 6) + (nf << 4) + c;
      if (o < 128) {
        uint2 pk2 = make_uint2(pkbf(acc[mf][nf][0], acc[mf][nf][1]),
                               pkbf(acc[mf][nf][2], acc[mf][nf][3]));
        const int head = o >> 4;
        const int z = (b << 3) + head;
        const int y = p >> 6, xx = p & 63;
        const int nbb = ((y >> 3) << 3) + (xx >> 3);
        const int qi = ((y & 7) << 3) + (xx & 7);
        *(uint2*)(q_bf + (((size_t)z * 64 + nbb) * 64 + qi) * 16 + (o & 15)) = pk2;
      } else {
        const int ch = o - 128;
        const int head = (ch * 1366) >> 16;      // ch/48
        const int wi = ch - head * 48;
        const int b8h = (b << 3) + head;
        if (wi < 16) {
          uint2 pk2 = make_uint2(pkbf(acc[mf][nf][0], acc[mf][nf][1]),
                                 pkbf(acc[mf][nf][2], acc[mf][nf][3]));
          *(uint2*)(kbuf + ((size_t)b8h * 4096 + p) * 16 + wi) = pk2;
        } else {
          const int d = wi - 16;
          const int y = p >> 6, xx = p & 63;
          unsigned short* vp = vpln + (size_t)(b8h * 32 + d) * 5040
                               + (size_t)(y + 3) * 72 + (xx + 3);
          vp[0]     = (unsigned short)f2bf(acc[mf][nf][0]);
          vp[5040]  = (unsigned short)f2bf(acc[mf][nf][1]);
          vp[10080] = (unsigned short)f2bf(acc[mf][nf][2]);
          vp[15120] = (unsigned short)f2bf(acc[mf][nf][3]);
        }
      }
    }
  }
}

// ---------------- Kernel 2: halo attention, direct-fragment, barrier-free loop ----
__global__ __launch_bounds__(64, 2) void haloattn_attn_direct(
    const unsigned short* __restrict__ q_bf, const unsigned short* __restrict__ kbuf,
    const unsigned short* __restrict__ vpln,
    const float* __restrict__ height_rel, const float* __restrict__ width_rel,
    float* __restrict__ out)
{
  __shared__ __align__(16) unsigned short SM[5376];   // 10.75 KB

  const int l = threadIdx.x;
  const int q32 = l & 31, hi = l >> 5;
  const int nb = blockIdx.x, z = blockIdx.y;
  const int b = z >> 3, head = z & 7;
  const int bi = nb >> 3, bj = nb & 7;
  const int swapA = (l ^ 32) << 2;
  const f32x16 z16 = {};
  const float qs = 0.25f * LOG2E;

  // ---- Q fragments (B-operand) ----
  const unsigned short* qtile = q_bf + ((size_t)z * 64 + nb) * 1024;
  bf16x8 qfrag[2];
  qfrag[0] = *(const bf16x8*)(qtile + q32 * 16 + 8 * hi);
  qfrag[1] = *(const bf16x8*)(qtile + (32 + q32) * 16 + 8 * hi);

  // ---- stage rel tables (bf16 * LOG2E) ----
  unsigned short* HRs = SM;          // [32][24]
  unsigned short* WRs = SM + 768;    // [32][24]
  if (l < 54) {
    const int u = l >> 1, d0 = (l & 1) << 3;
    float4 a = *(const float4*)(height_rel + u * 16 + d0);
    float4 b4 = *(const float4*)(height_rel + u * 16 + d0 + 4);
    uint4 o;
    o.x = cvtpk(a.x * LOG2E, a.y * LOG2E);
    o.y = cvtpk(a.z * LOG2E, a.w * LOG2E);
    o.z = cvtpk(b4.x * LOG2E, b4.y * LOG2E);
    o.w = cvtpk(b4.z * LOG2E, b4.w * LOG2E);
    *(uint4*)(HRs + u * 24 + d0) = o;
    a = *(const float4*)(width_rel + u * 16 + d0);
    b4 = *(const float4*)(width_rel + u * 16 + d0 + 4);
    o.x = cvtpk(a.x * LOG2E, a.y * LOG2E);
    o.y = cvtpk(a.z * LOG2E, a.w * LOG2E);
    o.z = cvtpk(b4.x * LOG2E, b4.y * LOG2E);
    o.w = cvtpk(b4.z * LOG2E, b4.w * LOG2E);
    *(uint4*)(WRs + u * 24 + d0) = o;
  } else {
    const int t = l - 54;
    const int u = 27 + (t >> 1), d0 = (t & 1) << 3;
    uint4 o = {};
    *(uint4*)(HRs + u * 24 + d0) = o;
    *(uint4*)(WRs + u * 24 + d0) = o;
  }
  __syncthreads();

  // ---- pos-embed tables via MFMA, stored bf16 [nt][21][64] (H at 0, W at 2688) ----
  {
    bf16x8 hfr = *(const bf16x8*)((const char*)HRs + q32 * 48 + 16 * hi);
    bf16x8 wfr = *(const bf16x8*)((const char*)WRs + q32 * 48 + 16 * hi);
    f32x16 h0 = __builtin_amdgcn_mfma_f32_32x32x16_bf16(hfr, qfrag[0], z16, 0, 0, 0);
    f32x16 h1 = __builtin_amdgcn_mfma_f32_32x32x16_bf16(hfr, qfrag[1], z16, 0, 0, 0);
    f32x16 w0 = __builtin_amdgcn_mfma_f32_32x32x16_bf16(wfr, qfrag[0], z16, 0, 0, 0);
    f32x16 w1 = __builtin_amdgcn_mfma_f32_32x32x16_bf16(wfr, qfrag[1], z16, 0, 0, 0);
    __syncthreads();   // staging reads complete before overwrite
#pragma unroll
    for (int r = 0; r < 16; ++r) {
      const int u = (r & 3) + 8 * (r >> 2) + 4 * hi;
      if (u >= 6 && u < 27) {
        const int rr = u - 6;
        SM[rr * 64 + q32]               = (unsigned short)f2bf(h0[r]);
        SM[(21 + rr) * 64 + q32]        = (unsigned short)f2bf(h1[r]);
        SM[2688 + rr * 64 + q32]        = (unsigned short)f2bf(w0[r]);
        SM[2688 + (21 + rr) * 64 + q32] = (unsigned short)f2bf(w1[r]);
      }
    }
  }
  __syncthreads();

  // ---- W bias preload (16 f32 regs); j>=14 slots become -1e30 masks ----
  const int qw = q32 & 7;
  float wreg[2][8];
#pragma unroll
  for (int nt = 0; nt < 2; ++nt)
#pragma unroll
    for (int t = 0; t < 8; ++t) {
      const int jt = (t < 4 ? t : t + 4) + 4 * hi;
      if (jt < 14)
        wreg[nt][t] = bfu2f(SM[2688 + (nt * 21 + 7 - qw + jt) * 64 + q32]);
      else
        wreg[nt][t] = -1e30f;
    }

  // ---- H bias LDS read bases ----
  const int qh0 = q32 >> 3;
  const unsigned short* Hp0 = SM + (7 - qh0) * 64 + q32;
  const unsigned short* Hp1 = SM + (24 - qh0) * 64 + q32;

  // ---- main loop: direct global fragments, 1-deep prefetch, no barriers ----
  const int jj = q32 & 15, ir = q32 >> 4;
  const int xx = bj * 8 + jj - 3;
  const bool jok = (jj < 14) && ((unsigned)xx < 64u);
  const unsigned short* kb = kbuf + ((size_t)((b << 3) + head) * 4096 + xx) * 16 + 8 * hi;
  const int yy0 = bi * 8 + ir - 3;
  const unsigned short* vb = vpln + (size_t)(((b << 3) + head) * 32 + q32) * 5040
                             + (bi * 8) * 72 + bj * 8 + 8 * hi;

  f32x16 acc[2] = {};
  float lrow[2] = {0.f, 0.f};

  KU k4; k4.u = make_uint4(0, 0, 0, 0);
  if (jok && (unsigned)yy0 < 64u) k4.u = *(const uint4*)(kb + (size_t)yy0 * 1024);
  bf16x8 v0n = *(const bf16x8*)(vb);
  bf16x8 v1n = *(const bf16x8*)(vb + 72);

  for (int c = 0; c < 7; ++c) {
    const bf16x8 kf = k4.v;
    const bf16x8 vf0 = v0n, vf1 = v1n;
    if (c < 6) {
      const int yy = yy0 + 2 * (c + 1);
      KU kn; kn.u = make_uint4(0, 0, 0, 0);
      if (jok && (unsigned)yy < 64u) kn.u = *(const uint4*)(kb + (size_t)yy * 1024);
      k4 = kn;
      v0n = *(const bf16x8*)(vb + (2 * c + 2) * 72);
      v1n = *(const bf16x8*)(vb + (2 * c + 3) * 72);
    }
#pragma unroll
    for (int nt = 0; nt < 2; ++nt) {
      f32x16 Cs = __builtin_amdgcn_mfma_f32_32x32x16_bf16(kf, qfrag[nt], z16, 0, 0, 0);
      const unsigned short* Hp = nt ? Hp1 : Hp0;
      const float hA = bfu2f(Hp[(2 * c) * 64]);
      const float hB = bfu2f(Hp[(2 * c + 1) * 64]);
      float p[16];
#pragma unroll
      for (int r = 0; r < 16; ++r) {
        const float wv = wreg[nt][(r & 3) + 4 * ((r >> 2) & 1)];
        const float h = (r < 8) ? hA : hB;
        p[r] = exp2f(fmaf(Cs[r], qs, h + wv));
      }
      {
        float s0 = (p[0] + p[1]) + (p[2] + p[3]);
        float s1 = (p[4] + p[5]) + (p[6] + p[7]);
        float s2 = (p[8] + p[9]) + (p[10] + p[11]);
        float s3 = (p[12] + p[13]) + (p[14] + p[15]);
        lrow[nt] += (s0 + s1) + (s2 + s3);
      }
      unsigned dw[8], xw[8];
#pragma unroll
      for (int k = 0; k < 8; ++k) dw[k] = cvtpk(p[2 * k], p[2 * k + 1]);
#pragma unroll
      for (int k = 0; k < 8; ++k)
        xw[k] = (unsigned)__builtin_amdgcn_ds_bpermute(swapA, (int)dw[k]);
      FragU8 f0, f1;
      f0.d[0] = hi ? xw[2] : dw[0];
      f0.d[1] = hi ? xw[3] : dw[1];
      f0.d[2] = hi ? dw[2] : xw[0];
      f0.d[3] = hi ? dw[3] : xw[1];
      f1.d[0] = hi ? xw[6] : dw[4];
      f1.d[1] = hi ? xw[7] : dw[5];
      f1.d[2] = hi ? dw[6] : xw[4];
      f1.d[3] = hi ? dw[7] : xw[5];
      acc[nt] = __builtin_amdgcn_mfma_f32_32x32x16_bf16(vf0, f0.v, acc[nt], 0, 0, 0);
      acc[nt] = __builtin_amdgcn_mfma_f32_32x32x16_bf16(vf1, f1.v, acc[nt], 0, 0, 0);
    }
  }

  // ---- epilogue ----
#pragma unroll
  for (int nt = 0; nt < 2; ++nt) {
    const float L = lrow[nt] + __shfl_xor(lrow[nt], 32);
    const float invL = 1.f / L;
    const int qt = nt * 32 + q32;
    const int yq = bi * 8 + (qt >> 3);
    const int xq = bj * 8 + (q32 & 7);
    float* obase = out + ((size_t)(b * 256 + head * 32) * 4096) + yq * 64 + xq;
#pragma unroll
    for (int r = 0; r < 16; ++r) {
      const int d = (r & 3) + 8 * (r >> 2) + 4 * hi;
      obase[(size_t)d * 4096] = acc[nt][r] * invL;
    }
  }
}

extern "C" void kernel_launch(void* const* d_in, const int* in_sizes, int n_in,
                              void* d_out, int out_size, void* d_ws, size_t ws_size,
                              hipStream_t stream) {
  const float* x          = (const float*)d_in[0];
  const float* q_w        = (const float*)d_in[1];
  const float* kv_w       = (const float*)d_in[2];
  const float* height_rel = (const float*)d_in[3];
  const float* width_rel  = (const float*)d_in[4];
  float* out = (float*)d_out;

  unsigned short* q_bf = (unsigned short*)d_ws;            // 4,194,304 u16
  unsigned short* xT   = q_bf + (size_t)4194304;           // 8,388,608 u16
  unsigned short* w_bf = xT + (size_t)8388608;             //   131,072 u16
  unsigned short* kbuf = w_bf + (size_t)131072;            // 4,194,304 u16
  unsigned short* vpln = kbuf + (size_t)4194304;           // 10,321,920 u16

  hipMemsetAsync(vpln, 0, (size_t)10321920 * 2, stream);
  haloattn_cvt<<<dim3(64, 4, 8), 256, 0, stream>>>(x, q_w, kv_w, xT, w_bf);
  haloattn_proj_mfma<<<dim3(32, 2, 8), 512, 0, stream>>>(xT, w_bf, q_bf, kbuf, vpln);
  haloattn_attn_direct<<<dim3(64, 64), 64, 0, stream>>>(q_bf, kbuf, vpln,
                                                        height_rel, width_rel, out);
}

// Round 7
// 77.257 us; speedup vs baseline: 1.5644x; 1.3073x over previous
//
#include <hip/hip_runtime.h>
#include <hip/hip_bf16.h>

#define LOG2E 1.4426950408889634f

typedef __attribute__((ext_vector_type(8))) short bf16x8;
typedef __attribute__((ext_vector_type(4))) float f32x4;
typedef __attribute__((ext_vector_type(16))) float f32x16;

__device__ __forceinline__ short f2bf(float a) {
  __hip_bfloat16 h = __float2bfloat16(a);
  return *reinterpret_cast<short*>(&h);
}
__device__ __forceinline__ unsigned pkbf(float a, float b) {
  return (unsigned)(unsigned short)f2bf(a) | ((unsigned)(unsigned short)f2bf(b) << 16);
}
__device__ __forceinline__ unsigned cvtpk(float a, float b) {
  unsigned r;
  asm("v_cvt_pk_bf16_f32 %0, %1, %2" : "=v"(r) : "v"(a), "v"(b));
  return r;
}
__device__ __forceinline__ float bfu2f(unsigned u16v) {
  unsigned v = u16v << 16; float f; __builtin_memcpy(&f, &v, 4); return f;
}
union FragU8 { unsigned d[4]; bf16x8 v; };
union KU { uint4 u; bf16x8 v; };

// ---------------- Kernel 0: transpose-convert ----------------
__global__ __launch_bounds__(256) void haloattn_cvt(
    const float* __restrict__ x, const float* __restrict__ q_w,
    const float* __restrict__ kv_w, unsigned short* __restrict__ xT,
    unsigned short* __restrict__ w_bf)
{
  __shared__ float Ld[64][68];
  const int t = threadIdx.x;
  const int pt = blockIdx.x, kt = blockIdx.y, b = blockIdx.z;
  {
    const int flat = ((b << 2) + kt) * 64 + pt;
    const int idx = flat * 64 + (t & 63);
    if (t < 64) {
      const float wv = (idx < 32768) ? q_w[idx] : kv_w[idx - 32768];
      w_bf[idx] = (unsigned short)f2bf(wv);
    }
  }
  const float* xb = x + ((size_t)b * 256 + (kt << 6)) * 4096 + (pt << 6);
#pragma unroll
  for (int ps = 0; ps < 4; ++ps) {
    const int kloc = (ps << 4) + (t >> 4);
    const int ploc = (t & 15) << 2;
    float4 v = *(const float4*)(xb + (size_t)kloc * 4096 + ploc);
    *(float4*)&Ld[kloc][ploc] = v;
  }
  __syncthreads();
  const int pl = t >> 2;
  const int ks = (t & 3) << 4;
  float f[16];
#pragma unroll
  for (int i = 0; i < 16; ++i) f[i] = Ld[ks + i][pl];
  uint4 o0, o1;
  o0.x = pkbf(f[0], f[1]);   o0.y = pkbf(f[2], f[3]);
  o0.z = pkbf(f[4], f[5]);   o0.w = pkbf(f[6], f[7]);
  o1.x = pkbf(f[8], f[9]);   o1.y = pkbf(f[10], f[11]);
  o1.z = pkbf(f[12], f[13]); o1.w = pkbf(f[14], f[15]);
  unsigned short* op = xT + ((size_t)(b << 12) + (pt << 6) + pl) * 256 + (kt << 6) + ks;
  *(uint4*)op = o0;
  *(uint4*)(op + 8) = o1;
}

// ---------------- Kernel 1: fused q/kv projection (bf16 MFMA) ----------------
__global__ __launch_bounds__(512, 4) void haloattn_proj_mfma(
    const unsigned short* __restrict__ xT, const unsigned short* __restrict__ w_bf,
    unsigned short* __restrict__ q_bf, unsigned short* __restrict__ kbuf,
    unsigned short* __restrict__ vpln)
{
  __shared__ unsigned short Wt[256][68];
  __shared__ unsigned short Xt[128][68];
  const int tid = threadIdx.x;
  const int w = tid >> 6, l = tid & 63;
  const int b = blockIdx.z, oBase = blockIdx.y << 8, pBase = blockIdx.x << 7;
  const int wm = w >> 1, wn = w & 1;
  const int g = l >> 4, c = l & 15;

  f32x4 acc[4][4] = {};

  const int srow = tid >> 3;
  const int se3  = (tid & 7) << 3;

  for (int chk = 0; chk < 4; ++chk) {
    const int k0 = chk << 6;
#pragma unroll
    for (int ps = 0; ps < 4; ++ps) {
      const int row = (ps << 6) + srow;
      uint4 wv = *(const uint4*)(w_bf + (size_t)(oBase + row) * 256 + k0 + se3);
      char* dst = (char*)&Wt[0][0] + row * 136 + (se3 << 1);
      *(uint2*)dst = make_uint2(wv.x, wv.y);
      *(uint2*)(dst + 8) = make_uint2(wv.z, wv.w);
    }
#pragma unroll
    for (int ps = 0; ps < 2; ++ps) {
      const int p = (ps << 6) + srow;
      uint4 xv = *(const uint4*)(xT + ((size_t)(b << 12) + pBase + p) * 256 + k0 + se3);
      char* dst = (char*)&Xt[0][0] + p * 136 + (se3 << 1);
      *(uint2*)dst = make_uint2(xv.x, xv.y);
      *(uint2*)(dst + 8) = make_uint2(xv.z, xv.w);
    }
    __syncthreads();
#pragma unroll
    for (int kk = 0; kk < 2; ++kk) {
      FragU8 bfr[4];
#pragma unroll
      for (int nf = 0; nf < 4; ++nf) {
        const char* src = (const char*)&Xt[0][0]
            + ((wn << 6) + (nf << 4) + c) * 136 + (kk << 6) + (g << 4);
        uint2 lo = *(const uint2*)src, hi2 = *(const uint2*)(src + 8);
        bfr[nf].d[0] = lo.x; bfr[nf].d[1] = lo.y;
        bfr[nf].d[2] = hi2.x; bfr[nf].d[3] = hi2.y;
      }
#pragma unroll
      for (int mf = 0; mf < 4; ++mf) {
        const char* src = (const char*)&Wt[0][0]
            + ((wm << 6) + (mf << 4) + c) * 136 + (kk << 6) + (g << 4);
        uint2 lo = *(const uint2*)src, hi2 = *(const uint2*)(src + 8);
        FragU8 af;
        af.d[0] = lo.x; af.d[1] = lo.y; af.d[2] = hi2.x; af.d[3] = hi2.y;
#pragma unroll
        for (int nf = 0; nf < 4; ++nf)
          acc[mf][nf] = __builtin_amdgcn_mfma_f32_16x16x32_bf16(af.v, bfr[nf].v, acc[mf][nf], 0, 0, 0);
      }
    }
    __syncthreads();
  }
#pragma unroll
  for (int mf = 0; mf < 4; ++mf) {
    const int o = oBase + (wm << 6) + (mf << 4) + (g << 2);
#pragma unroll
    for (int nf = 0; nf < 4; ++nf) {
      const int p = pBase + (wn << 6) + (nf << 4) + c;
      if (o < 128) {
        uint2 pk2 = make_uint2(pkbf(acc[mf][nf][0], acc[mf][nf][1]),
                               pkbf(acc[mf][nf][2], acc[mf][nf][3]));
        const int head = o >> 4;
        const int z = (b << 3) + head;
        const int y = p >> 6, xx = p & 63;
        const int nbb = ((y >> 3) << 3) + (xx >> 3);
        const int qi = ((y & 7) << 3) + (xx & 7);
        *(uint2*)(q_bf + (((size_t)z * 64 + nbb) * 64 + qi) * 16 + (o & 15)) = pk2;
      } else {
        const int ch = o - 128;
        const int head = (ch * 1366) >> 16;      // ch/48
        const int wi = ch - head * 48;
        const int b8h = (b << 3) + head;
        if (wi < 16) {
          uint2 pk2 = make_uint2(pkbf(acc[mf][nf][0], acc[mf][nf][1]),
                                 pkbf(acc[mf][nf][2], acc[mf][nf][3]));
          *(uint2*)(kbuf + ((size_t)b8h * 4096 + p) * 16 + wi) = pk2;
        } else {
          const int d = wi - 16;
          const int y = p >> 6, xx = p & 63;
          unsigned short* vp = vpln + (size_t)(b8h * 32 + d) * 5040
                               + (size_t)(y + 3) * 72 + (xx + 3);
          vp[0]     = (unsigned short)f2bf(acc[mf][nf][0]);
          vp[5040]  = (unsigned short)f2bf(acc[mf][nf][1]);
          vp[10080] = (unsigned short)f2bf(acc[mf][nf][2]);
          vp[15120] = (unsigned short)f2bf(acc[mf][nf][3]);
        }
      }
    }
  }
}

// ---------------- Kernel 2: halo attention, direct-fragment, XCD-swizzled ----
__global__ __launch_bounds__(64, 2) void haloattn_attn_direct(
    const unsigned short* __restrict__ q_bf, const unsigned short* __restrict__ kbuf,
    const unsigned short* __restrict__ vpln,
    const float* __restrict__ height_rel, const float* __restrict__ width_rel,
    float* __restrict__ out)
{
  __shared__ __align__(16) unsigned short SM[5376];   // 10.75 KB

  const int l = threadIdx.x;
  const int q32 = l & 31, hi = l >> 5;
  // XCD-aware swizzle: consecutive-resident blocks share (z, adjacent nb) lines.
  // nwg = 4096, 8 XCDs, 4096 % 8 == 0 -> bijective.
  const int wg = blockIdx.x;
  const int swz = ((wg & 7) << 9) | (wg >> 3);
  const int z = swz >> 6;
  const int nb = swz & 63;
  const int b = z >> 3, head = z & 7;
  const int bi = nb >> 3, bj = nb & 7;
  const int swapA = (l ^ 32) << 2;
  const f32x16 z16 = {};
  const float qs = 0.25f * LOG2E;

  // ---- Q fragments (B-operand) ----
  const unsigned short* qtile = q_bf + ((size_t)z * 64 + nb) * 1024;
  bf16x8 qfrag[2];
  qfrag[0] = *(const bf16x8*)(qtile + q32 * 16 + 8 * hi);
  qfrag[1] = *(const bf16x8*)(qtile + (32 + q32) * 16 + 8 * hi);

  // ---- stage rel tables (bf16 * LOG2E) ----
  unsigned short* HRs = SM;          // [32][24]
  unsigned short* WRs = SM + 768;    // [32][24]
  if (l < 54) {
    const int u = l >> 1, d0 = (l & 1) << 3;
    float4 a = *(const float4*)(height_rel + u * 16 + d0);
    float4 b4 = *(const float4*)(height_rel + u * 16 + d0 + 4);
    uint4 o;
    o.x = cvtpk(a.x * LOG2E, a.y * LOG2E);
    o.y = cvtpk(a.z * LOG2E, a.w * LOG2E);
    o.z = cvtpk(b4.x * LOG2E, b4.y * LOG2E);
    o.w = cvtpk(b4.z * LOG2E, b4.w * LOG2E);
    *(uint4*)(HRs + u * 24 + d0) = o;
    a = *(const float4*)(width_rel + u * 16 + d0);
    b4 = *(const float4*)(width_rel + u * 16 + d0 + 4);
    o.x = cvtpk(a.x * LOG2E, a.y * LOG2E);
    o.y = cvtpk(a.z * LOG2E, a.w * LOG2E);
    o.z = cvtpk(b4.x * LOG2E, b4.y * LOG2E);
    o.w = cvtpk(b4.z * LOG2E, b4.w * LOG2E);
    *(uint4*)(WRs + u * 24 + d0) = o;
  } else {
    const int t = l - 54;
    const int u = 27 + (t >> 1), d0 = (t & 1) << 3;
    uint4 o = {};
    *(uint4*)(HRs + u * 24 + d0) = o;
    *(uint4*)(WRs + u * 24 + d0) = o;
  }
  __syncthreads();

  // ---- pos-embed tables via MFMA, stored bf16 [nt][21][64] (H at 0, W at 2688) ----
  {
    bf16x8 hfr = *(const bf16x8*)((const char*)HRs + q32 * 48 + 16 * hi);
    bf16x8 wfr = *(const bf16x8*)((const char*)WRs + q32 * 48 + 16 * hi);
    f32x16 h0 = __builtin_amdgcn_mfma_f32_32x32x16_bf16(hfr, qfrag[0], z16, 0, 0, 0);
    f32x16 h1 = __builtin_amdgcn_mfma_f32_32x32x16_bf16(hfr, qfrag[1], z16, 0, 0, 0);
    f32x16 w0 = __builtin_amdgcn_mfma_f32_32x32x16_bf16(wfr, qfrag[0], z16, 0, 0, 0);
    f32x16 w1 = __builtin_amdgcn_mfma_f32_32x32x16_bf16(wfr, qfrag[1], z16, 0, 0, 0);
    __syncthreads();   // staging reads complete before overwrite
#pragma unroll
    for (int r = 0; r < 16; ++r) {
      const int u = (r & 3) + 8 * (r >> 2) + 4 * hi;
      if (u >= 6 && u < 27) {
        const int rr = u - 6;
        SM[rr * 64 + q32]               = (unsigned short)f2bf(h0[r]);
        SM[(21 + rr) * 64 + q32]        = (unsigned short)f2bf(h1[r]);
        SM[2688 + rr * 64 + q32]        = (unsigned short)f2bf(w0[r]);
        SM[2688 + (21 + rr) * 64 + q32] = (unsigned short)f2bf(w1[r]);
      }
    }
  }
  __syncthreads();

  // ---- W bias preload (16 f32 regs); j>=14 slots become -1e30 masks ----
  const int qw = q32 & 7;
  float wreg[2][8];
#pragma unroll
  for (int nt = 0; nt < 2; ++nt)
#pragma unroll
    for (int t = 0; t < 8; ++t) {
      const int jt = (t < 4 ? t : t + 4) + 4 * hi;
      if (jt < 14)
        wreg[nt][t] = bfu2f(SM[2688 + (nt * 21 + 7 - qw + jt) * 64 + q32]);
      else
        wreg[nt][t] = -1e30f;
    }

  // ---- H bias LDS read bases ----
  const int qh0 = q32 >> 3;
  const unsigned short* Hp0 = SM + (7 - qh0) * 64 + q32;
  const unsigned short* Hp1 = SM + (24 - qh0) * 64 + q32;

  // ---- main loop: direct global fragments, 1-deep prefetch, no barriers ----
  const int jj = q32 & 15, ir = q32 >> 4;
  const int xx = bj * 8 + jj - 3;
  const bool jok = (jj < 14) && ((unsigned)xx < 64u);
  const unsigned short* kb = kbuf + ((size_t)((b << 3) + head) * 4096 + xx) * 16 + 8 * hi;
  const int yy0 = bi * 8 + ir - 3;
  const unsigned short* vb = vpln + (size_t)(((b << 3) + head) * 32 + q32) * 5040
                             + (bi * 8) * 72 + bj * 8 + 8 * hi;

  f32x16 acc[2] = {};
  float lrow[2] = {0.f, 0.f};

  KU k4; k4.u = make_uint4(0, 0, 0, 0);
  if (jok && (unsigned)yy0 < 64u) k4.u = *(const uint4*)(kb + (size_t)yy0 * 1024);
  bf16x8 v0n = *(const bf16x8*)(vb);
  bf16x8 v1n = *(const bf16x8*)(vb + 72);

  for (int c = 0; c < 7; ++c) {
    const bf16x8 kf = k4.v;
    const bf16x8 vf0 = v0n, vf1 = v1n;
    if (c < 6) {
      const int yy = yy0 + 2 * (c + 1);
      KU kn; kn.u = make_uint4(0, 0, 0, 0);
      if (jok && (unsigned)yy < 64u) kn.u = *(const uint4*)(kb + (size_t)yy * 1024);
      k4 = kn;
      v0n = *(const bf16x8*)(vb + (2 * c + 2) * 72);
      v1n = *(const bf16x8*)(vb + (2 * c + 3) * 72);
    }
#pragma unroll
    for (int nt = 0; nt < 2; ++nt) {
      f32x16 Cs = __builtin_amdgcn_mfma_f32_32x32x16_bf16(kf, qfrag[nt], z16, 0, 0, 0);
      const unsigned short* Hp = nt ? Hp1 : Hp0;
      const float hA = bfu2f(Hp[(2 * c) * 64]);
      const float hB = bfu2f(Hp[(2 * c + 1) * 64]);
      float p[16];
#pragma unroll
      for (int r = 0; r < 16; ++r) {
        const float wv = wreg[nt][(r & 3) + 4 * ((r >> 2) & 1)];
        const float h = (r < 8) ? hA : hB;
        p[r] = exp2f(fmaf(Cs[r], qs, h + wv));
      }
      {
        float s0 = (p[0] + p[1]) + (p[2] + p[3]);
        float s1 = (p[4] + p[5]) + (p[6] + p[7]);
        float s2 = (p[8] + p[9]) + (p[10] + p[11]);
        float s3 = (p[12] + p[13]) + (p[14] + p[15]);
        lrow[nt] += (s0 + s1) + (s2 + s3);
      }
      unsigned dw[8], xw[8];
#pragma unroll
      for (int k = 0; k < 8; ++k) dw[k] = cvtpk(p[2 * k], p[2 * k + 1]);
#pragma unroll
      for (int k = 0; k < 8; ++k)
        xw[k] = (unsigned)__builtin_amdgcn_ds_bpermute(swapA, (int)dw[k]);
      FragU8 f0, f1;
      f0.d[0] = hi ? xw[2] : dw[0];
      f0.d[1] = hi ? xw[3] : dw[1];
      f0.d[2] = hi ? dw[2] : xw[0];
      f0.d[3] = hi ? dw[3] : xw[1];
      f1.d[0] = hi ? xw[6] : dw[4];
      f1.d[1] = hi ? xw[7] : dw[5];
      f1.d[2] = hi ? dw[6] : xw[4];
      f1.d[3] = hi ? dw[7] : xw[5];
      acc[nt] = __builtin_amdgcn_mfma_f32_32x32x16_bf16(vf0, f0.v, acc[nt], 0, 0, 0);
      acc[nt] = __builtin_amdgcn_mfma_f32_32x32x16_bf16(vf1, f1.v, acc[nt], 0, 0, 0);
    }
  }

  // ---- epilogue ----
#pragma unroll
  for (int nt = 0; nt < 2; ++nt) {
    const float L = lrow[nt] + __shfl_xor(lrow[nt], 32);
    const float invL = 1.f / L;
    const int qt = nt * 32 + q32;
    const int yq = bi * 8 + (qt >> 3);
    const int xq = bj * 8 + (q32 & 7);
    float* obase = out + ((size_t)(b * 256 + head * 32) * 4096) + yq * 64 + xq;
#pragma unroll
    for (int r = 0; r < 16; ++r) {
      const int d = (r & 3) + 8 * (r >> 2) + 4 * hi;
      obase[(size_t)d * 4096] = acc[nt][r] * invL;
    }
  }
}

extern "C" void kernel_launch(void* const* d_in, const int* in_sizes, int n_in,
                              void* d_out, int out_size, void* d_ws, size_t ws_size,
                              hipStream_t stream) {
  const float* x          = (const float*)d_in[0];
  const float* q_w        = (const float*)d_in[1];
  const float* kv_w       = (const float*)d_in[2];
  const float* height_rel = (const float*)d_in[3];
  const float* width_rel  = (const float*)d_in[4];
  float* out = (float*)d_out;

  unsigned short* q_bf = (unsigned short*)d_ws;            // 4,194,304 u16
  unsigned short* xT   = q_bf + (size_t)4194304;           // 8,388,608 u16
  unsigned short* w_bf = xT + (size_t)8388608;             //   131,072 u16
  unsigned short* kbuf = w_bf + (size_t)131072;            // 4,194,304 u16
  unsigned short* vpln = kbuf + (size_t)4194304;           // 10,321,920 u16

  hipMemsetAsync(vpln, 0, (size_t)10321920 * 2, stream);
  haloattn_cvt<<<dim3(64, 4, 8), 256, 0, stream>>>(x, q_w, kv_w, xT, w_bf);
  haloattn_proj_mfma<<<dim3(32, 2, 8), 512, 0, stream>>>(xT, w_bf, q_bf, kbuf, vpln);
  haloattn_attn_direct<<<4096, 64, 0, stream>>>(q_bf, kbuf, vpln,
                                                height_rel, width_rel, out);
}

// Round 8
// 71.544 us; speedup vs baseline: 1.6894x; 1.0799x over previous
//
#include <hip/hip_runtime.h>
#include <hip/hip_bf16.h>

#define LOG2E 1.4426950408889634f

typedef __attribute__((ext_vector_type(8))) short bf16x8;
typedef __attribute__((ext_vector_type(4))) float f32x4;
typedef __attribute__((ext_vector_type(16))) float f32x16;

__device__ __forceinline__ short f2bf(float a) {
  __hip_bfloat16 h = __float2bfloat16(a);
  return *reinterpret_cast<short*>(&h);
}
__device__ __forceinline__ unsigned pkbf(float a, float b) {
  return (unsigned)(unsigned short)f2bf(a) | ((unsigned)(unsigned short)f2bf(b) << 16);
}
__device__ __forceinline__ unsigned cvtpk(float a, float b) {
  unsigned r;
  asm("v_cvt_pk_bf16_f32 %0, %1, %2" : "=v"(r) : "v"(a), "v"(b));
  return r;
}
__device__ __forceinline__ float bfu2f(unsigned u16v) {
  unsigned v = u16v << 16; float f; __builtin_memcpy(&f, &v, 4); return f;
}
union FragU8 { unsigned d[4]; bf16x8 v; };
union KU { uint4 u; bf16x8 v; };

// ---------------- Kernel Z: zero the V-plane halo borders only ----------------
// vpln = [2048 planes][70][72] u16. Interior rows 3..66 x cols 3..66 is fully
// rewritten by proj every call; only the 944 border elems/plane need zeroing.
__global__ __launch_bounds__(256) void haloattn_zero_border(
    unsigned short* __restrict__ vpln)
{
  unsigned short* pl = vpln + (size_t)blockIdx.x * 5040;
  for (int e = threadIdx.x; e < 944; e += 256) {
    int off;
    if (e < 216) {
      off = e;                       // rows 0-2
    } else if (e < 432) {
      off = 4824 + (e - 216);        // rows 67-69
    } else {
      const int t = e - 432;         // 512 middle-border elems
      const int y = 3 + (t >> 3);
      const int cidx = t & 7;        // 0,1,2 -> cols 0-2 ; 3..7 -> cols 67-71
      off = y * 72 + (cidx < 3 ? cidx : cidx + 64);
    }
    pl[off] = 0;
  }
}

// ---------------- Kernel 0: transpose-convert ----------------
__global__ __launch_bounds__(256) void haloattn_cvt(
    const float* __restrict__ x, const float* __restrict__ q_w,
    const float* __restrict__ kv_w, unsigned short* __restrict__ xT,
    unsigned short* __restrict__ w_bf)
{
  __shared__ float Ld[64][68];
  const int t = threadIdx.x;
  const int pt = blockIdx.x, kt = blockIdx.y, b = blockIdx.z;
  {
    const int flat = ((b << 2) + kt) * 64 + pt;
    const int idx = flat * 64 + (t & 63);
    if (t < 64) {
      const float wv = (idx < 32768) ? q_w[idx] : kv_w[idx - 32768];
      w_bf[idx] = (unsigned short)f2bf(wv);
    }
  }
  const float* xb = x + ((size_t)b * 256 + (kt << 6)) * 4096 + (pt << 6);
#pragma unroll
  for (int ps = 0; ps < 4; ++ps) {
    const int kloc = (ps << 4) + (t >> 4);
    const int ploc = (t & 15) << 2;
    float4 v = *(const float4*)(xb + (size_t)kloc * 4096 + ploc);
    *(float4*)&Ld[kloc][ploc] = v;
  }
  __syncthreads();
  const int pl = t >> 2;
  const int ks = (t & 3) << 4;
  float f[16];
#pragma unroll
  for (int i = 0; i < 16; ++i) f[i] = Ld[ks + i][pl];
  uint4 o0, o1;
  o0.x = pkbf(f[0], f[1]);   o0.y = pkbf(f[2], f[3]);
  o0.z = pkbf(f[4], f[5]);   o0.w = pkbf(f[6], f[7]);
  o1.x = pkbf(f[8], f[9]);   o1.y = pkbf(f[10], f[11]);
  o1.z = pkbf(f[12], f[13]); o1.w = pkbf(f[14], f[15]);
  unsigned short* op = xT + ((size_t)(b << 12) + (pt << 6) + pl) * 256 + (kt << 6) + ks;
  *(uint4*)op = o0;
  *(uint4*)(op + 8) = o1;
}

// ---------------- Kernel 1: fused q/kv projection (bf16 MFMA) ----------------
__global__ __launch_bounds__(512, 4) void haloattn_proj_mfma(
    const unsigned short* __restrict__ xT, const unsigned short* __restrict__ w_bf,
    unsigned short* __restrict__ q_bf, unsigned short* __restrict__ kbuf,
    unsigned short* __restrict__ vpln)
{
  __shared__ unsigned short Wt[256][68];
  __shared__ unsigned short Xt[128][68];
  const int tid = threadIdx.x;
  const int w = tid >> 6, l = tid & 63;
  const int b = blockIdx.z, oBase = blockIdx.y << 8, pBase = blockIdx.x << 7;
  const int wm = w >> 1, wn = w & 1;
  const int g = l >> 4, c = l & 15;

  f32x4 acc[4][4] = {};

  const int srow = tid >> 3;
  const int se3  = (tid & 7) << 3;

  for (int chk = 0; chk < 4; ++chk) {
    const int k0 = chk << 6;
#pragma unroll
    for (int ps = 0; ps < 4; ++ps) {
      const int row = (ps << 6) + srow;
      uint4 wv = *(const uint4*)(w_bf + (size_t)(oBase + row) * 256 + k0 + se3);
      char* dst = (char*)&Wt[0][0] + row * 136 + (se3 << 1);
      *(uint2*)dst = make_uint2(wv.x, wv.y);
      *(uint2*)(dst + 8) = make_uint2(wv.z, wv.w);
    }
#pragma unroll
    for (int ps = 0; ps < 2; ++ps) {
      const int p = (ps << 6) + srow;
      uint4 xv = *(const uint4*)(xT + ((size_t)(b << 12) + pBase + p) * 256 + k0 + se3);
      char* dst = (char*)&Xt[0][0] + p * 136 + (se3 << 1);
      *(uint2*)dst = make_uint2(xv.x, xv.y);
      *(uint2*)(dst + 8) = make_uint2(xv.z, xv.w);
    }
    __syncthreads();
#pragma unroll
    for (int kk = 0; kk < 2; ++kk) {
      FragU8 bfr[4];
#pragma unroll
      for (int nf = 0; nf < 4; ++nf) {
        const char* src = (const char*)&Xt[0][0]
            + ((wn << 6) + (nf << 4) + c) * 136 + (kk << 6) + (g << 4);
        uint2 lo = *(const uint2*)src, hi2 = *(const uint2*)(src + 8);
        bfr[nf].d[0] = lo.x; bfr[nf].d[1] = lo.y;
        bfr[nf].d[2] = hi2.x; bfr[nf].d[3] = hi2.y;
      }
#pragma unroll
      for (int mf = 0; mf < 4; ++mf) {
        const char* src = (const char*)&Wt[0][0]
            + ((wm << 6) + (mf << 4) + c) * 136 + (kk << 6) + (g << 4);
        uint2 lo = *(const uint2*)src, hi2 = *(const uint2*)(src + 8);
        FragU8 af;
        af.d[0] = lo.x; af.d[1] = lo.y; af.d[2] = hi2.x; af.d[3] = hi2.y;
#pragma unroll
        for (int nf = 0; nf < 4; ++nf)
          acc[mf][nf] = __builtin_amdgcn_mfma_f32_16x16x32_bf16(af.v, bfr[nf].v, acc[mf][nf], 0, 0, 0);
      }
    }
    __syncthreads();
  }
#pragma unroll
  for (int mf = 0; mf < 4; ++mf) {
    const int o = oBase + (wm << 6) + (mf << 4) + (g << 2);
#pragma unroll
    for (int nf = 0; nf < 4; ++nf) {
      const int p = pBase + (wn << 6) + (nf << 4) + c;
      if (o < 128) {
        uint2 pk2 = make_uint2(pkbf(acc[mf][nf][0], acc[mf][nf][1]),
                               pkbf(acc[mf][nf][2], acc[mf][nf][3]));
        const int head = o >> 4;
        const int z = (b << 3) + head;
        const int y = p >> 6, xx = p & 63;
        const int nbb = ((y >> 3) << 3) + (xx >> 3);
        const int qi = ((y & 7) << 3) + (xx & 7);
        *(uint2*)(q_bf + (((size_t)z * 64 + nbb) * 64 + qi) * 16 + (o & 15)) = pk2;
      } else {
        const int ch = o - 128;
        const int head = (ch * 1366) >> 16;      // ch/48
        const int wi = ch - head * 48;
        const int b8h = (b << 3) + head;
        if (wi < 16) {
          uint2 pk2 = make_uint2(pkbf(acc[mf][nf][0], acc[mf][nf][1]),
                                 pkbf(acc[mf][nf][2], acc[mf][nf][3]));
          *(uint2*)(kbuf + ((size_t)b8h * 4096 + p) * 16 + wi) = pk2;
        } else {
          const int d = wi - 16;
          const int y = p >> 6, xx = p & 63;
          unsigned short* vp = vpln + (size_t)(b8h * 32 + d) * 5040
                               + (size_t)(y + 3) * 72 + (xx + 3);
          vp[0]     = (unsigned short)f2bf(acc[mf][nf][0]);
          vp[5040]  = (unsigned short)f2bf(acc[mf][nf][1]);
          vp[10080] = (unsigned short)f2bf(acc[mf][nf][2]);
          vp[15120] = (unsigned short)f2bf(acc[mf][nf][3]);
        }
      }
    }
  }
}

// ---------------- Kernel 2: halo attention, direct-fragment, XCD-swizzled ----
__global__ __launch_bounds__(64, 2) void haloattn_attn_direct(
    const unsigned short* __restrict__ q_bf, const unsigned short* __restrict__ kbuf,
    const unsigned short* __restrict__ vpln,
    const float* __restrict__ height_rel, const float* __restrict__ width_rel,
    float* __restrict__ out)
{
  __shared__ __align__(16) unsigned short SM[5376];   // 10.75 KB

  const int l = threadIdx.x;
  const int q32 = l & 31, hi = l >> 5;
  // XCD-aware swizzle: consecutive-resident blocks share (z, adjacent nb) lines.
  // nwg = 4096, 8 XCDs, 4096 % 8 == 0 -> bijective.
  const int wg = blockIdx.x;
  const int swz = ((wg & 7) << 9) | (wg >> 3);
  const int z = swz >> 6;
  const int nb = swz & 63;
  const int b = z >> 3, head = z & 7;
  const int bi = nb >> 3, bj = nb & 7;
  const int swapA = (l ^ 32) << 2;
  const f32x16 z16 = {};
  const float qs = 0.25f * LOG2E;

  // ---- Q fragments (B-operand) ----
  const unsigned short* qtile = q_bf + ((size_t)z * 64 + nb) * 1024;
  bf16x8 qfrag[2];
  qfrag[0] = *(const bf16x8*)(qtile + q32 * 16 + 8 * hi);
  qfrag[1] = *(const bf16x8*)(qtile + (32 + q32) * 16 + 8 * hi);

  // ---- stage rel tables (bf16 * LOG2E) ----
  unsigned short* HRs = SM;          // [32][24]
  unsigned short* WRs = SM + 768;    // [32][24]
  if (l < 54) {
    const int u = l >> 1, d0 = (l & 1) << 3;
    float4 a = *(const float4*)(height_rel + u * 16 + d0);
    float4 b4 = *(const float4*)(height_rel + u * 16 + d0 + 4);
    uint4 o;
    o.x = cvtpk(a.x * LOG2E, a.y * LOG2E);
    o.y = cvtpk(a.z * LOG2E, a.w * LOG2E);
    o.z = cvtpk(b4.x * LOG2E, b4.y * LOG2E);
    o.w = cvtpk(b4.z * LOG2E, b4.w * LOG2E);
    *(uint4*)(HRs + u * 24 + d0) = o;
    a = *(const float4*)(width_rel + u * 16 + d0);
    b4 = *(const float4*)(width_rel + u * 16 + d0 + 4);
    o.x = cvtpk(a.x * LOG2E, a.y * LOG2E);
    o.y = cvtpk(a.z * LOG2E, a.w * LOG2E);
    o.z = cvtpk(b4.x * LOG2E, b4.y * LOG2E);
    o.w = cvtpk(b4.z * LOG2E, b4.w * LOG2E);
    *(uint4*)(WRs + u * 24 + d0) = o;
  } else {
    const int t = l - 54;
    const int u = 27 + (t >> 1), d0 = (t & 1) << 3;
    uint4 o = {};
    *(uint4*)(HRs + u * 24 + d0) = o;
    *(uint4*)(WRs + u * 24 + d0) = o;
  }
  __syncthreads();

  // ---- pos-embed tables via MFMA, stored bf16 [nt][21][64] (H at 0, W at 2688) ----
  {
    bf16x8 hfr = *(const bf16x8*)((const char*)HRs + q32 * 48 + 16 * hi);
    bf16x8 wfr = *(const bf16x8*)((const char*)WRs + q32 * 48 + 16 * hi);
    f32x16 h0 = __builtin_amdgcn_mfma_f32_32x32x16_bf16(hfr, qfrag[0], z16, 0, 0, 0);
    f32x16 h1 = __builtin_amdgcn_mfma_f32_32x32x16_bf16(hfr, qfrag[1], z16, 0, 0, 0);
    f32x16 w0 = __builtin_amdgcn_mfma_f32_32x32x16_bf16(wfr, qfrag[0], z16, 0, 0, 0);
    f32x16 w1 = __builtin_amdgcn_mfma_f32_32x32x16_bf16(wfr, qfrag[1], z16, 0, 0, 0);
    __syncthreads();   // staging reads complete before overwrite
#pragma unroll
    for (int r = 0; r < 16; ++r) {
      const int u = (r & 3) + 8 * (r >> 2) + 4 * hi;
      if (u >= 6 && u < 27) {
        const int rr = u - 6;
        SM[rr * 64 + q32]               = (unsigned short)f2bf(h0[r]);
        SM[(21 + rr) * 64 + q32]        = (unsigned short)f2bf(h1[r]);
        SM[2688 + rr * 64 + q32]        = (unsigned short)f2bf(w0[r]);
        SM[2688 + (21 + rr) * 64 + q32] = (unsigned short)f2bf(w1[r]);
      }
    }
  }
  __syncthreads();

  // ---- W bias preload (16 f32 regs); j>=14 slots become -1e30 masks ----
  const int qw = q32 & 7;
  float wreg[2][8];
#pragma unroll
  for (int nt = 0; nt < 2; ++nt)
#pragma unroll
    for (int t = 0; t < 8; ++t) {
      const int jt = (t < 4 ? t : t + 4) + 4 * hi;
      if (jt < 14)
        wreg[nt][t] = bfu2f(SM[2688 + (nt * 21 + 7 - qw + jt) * 64 + q32]);
      else
        wreg[nt][t] = -1e30f;
    }

  // ---- H bias LDS read bases ----
  const int qh0 = q32 >> 3;
  const unsigned short* Hp0 = SM + (7 - qh0) * 64 + q32;
  const unsigned short* Hp1 = SM + (24 - qh0) * 64 + q32;

  // ---- main loop: direct global fragments, 1-deep prefetch, no barriers ----
  const int jj = q32 & 15, ir = q32 >> 4;
  const int xx = bj * 8 + jj - 3;
  const bool jok = (jj < 14) && ((unsigned)xx < 64u);
  const unsigned short* kb = kbuf + ((size_t)((b << 3) + head) * 4096 + xx) * 16 + 8 * hi;
  const int yy0 = bi * 8 + ir - 3;
  const unsigned short* vb = vpln + (size_t)(((b << 3) + head) * 32 + q32) * 5040
                             + (bi * 8) * 72 + bj * 8 + 8 * hi;

  f32x16 acc[2] = {};
  float lrow[2] = {0.f, 0.f};

  KU k4; k4.u = make_uint4(0, 0, 0, 0);
  if (jok && (unsigned)yy0 < 64u) k4.u = *(const uint4*)(kb + (size_t)yy0 * 1024);
  bf16x8 v0n = *(const bf16x8*)(vb);
  bf16x8 v1n = *(const bf16x8*)(vb + 72);

  for (int c = 0; c < 7; ++c) {
    const bf16x8 kf = k4.v;
    const bf16x8 vf0 = v0n, vf1 = v1n;
    if (c < 6) {
      const int yy = yy0 + 2 * (c + 1);
      KU kn; kn.u = make_uint4(0, 0, 0, 0);
      if (jok && (unsigned)yy < 64u) kn.u = *(const uint4*)(kb + (size_t)yy * 1024);
      k4 = kn;
      v0n = *(const bf16x8*)(vb + (2 * c + 2) * 72);
      v1n = *(const bf16x8*)(vb + (2 * c + 3) * 72);
    }
#pragma unroll
    for (int nt = 0; nt < 2; ++nt) {
      f32x16 Cs = __builtin_amdgcn_mfma_f32_32x32x16_bf16(kf, qfrag[nt], z16, 0, 0, 0);
      const unsigned short* Hp = nt ? Hp1 : Hp0;
      const float hA = bfu2f(Hp[(2 * c) * 64]);
      const float hB = bfu2f(Hp[(2 * c + 1) * 64]);
      float p[16];
#pragma unroll
      for (int r = 0; r < 16; ++r) {
        const float wv = wreg[nt][(r & 3) + 4 * ((r >> 2) & 1)];
        const float h = (r < 8) ? hA : hB;
        p[r] = exp2f(fmaf(Cs[r], qs, h + wv));
      }
      {
        float s0 = (p[0] + p[1]) + (p[2] + p[3]);
        float s1 = (p[4] + p[5]) + (p[6] + p[7]);
        float s2 = (p[8] + p[9]) + (p[10] + p[11]);
        float s3 = (p[12] + p[13]) + (p[14] + p[15]);
        lrow[nt] += (s0 + s1) + (s2 + s3);
      }
      unsigned dw[8], xw[8];
#pragma unroll
      for (int k = 0; k < 8; ++k) dw[k] = cvtpk(p[2 * k], p[2 * k + 1]);
#pragma unroll
      for (int k = 0; k < 8; ++k)
        xw[k] = (unsigned)__builtin_amdgcn_ds_bpermute(swapA, (int)dw[k]);
      FragU8 f0, f1;
      f0.d[0] = hi ? xw[2] : dw[0];
      f0.d[1] = hi ? xw[3] : dw[1];
      f0.d[2] = hi ? dw[2] : xw[0];
      f0.d[3] = hi ? dw[3] : xw[1];
      f1.d[0] = hi ? xw[6] : dw[4];
      f1.d[1] = hi ? xw[7] : dw[5];
      f1.d[2] = hi ? dw[6] : xw[4];
      f1.d[3] = hi ? dw[7] : xw[5];
      acc[nt] = __builtin_amdgcn_mfma_f32_32x32x16_bf16(vf0, f0.v, acc[nt], 0, 0, 0);
      acc[nt] = __builtin_amdgcn_mfma_f32_32x32x16_bf16(vf1, f1.v, acc[nt], 0, 0, 0);
    }
  }

  // ---- epilogue ----
#pragma unroll
  for (int nt = 0; nt < 2; ++nt) {
    const float L = lrow[nt] + __shfl_xor(lrow[nt], 32);
    const float invL = 1.f / L;
    const int qt = nt * 32 + q32;
    const int yq = bi * 8 + (qt >> 3);
    const int xq = bj * 8 + (q32 & 7);
    float* obase = out + ((size_t)(b * 256 + head * 32) * 4096) + yq * 64 + xq;
#pragma unroll
    for (int r = 0; r < 16; ++r) {
      const int d = (r & 3) + 8 * (r >> 2) + 4 * hi;
      obase[(size_t)d * 4096] = acc[nt][r] * invL;
    }
  }
}

extern "C" void kernel_launch(void* const* d_in, const int* in_sizes, int n_in,
                              void* d_out, int out_size, void* d_ws, size_t ws_size,
                              hipStream_t stream) {
  const float* x          = (const float*)d_in[0];
  const float* q_w        = (const float*)d_in[1];
  const float* kv_w       = (const float*)d_in[2];
  const float* height_rel = (const float*)d_in[3];
  const float* width_rel  = (const float*)d_in[4];
  float* out = (float*)d_out;

  unsigned short* q_bf = (unsigned short*)d_ws;            // 4,194,304 u16
  unsigned short* xT   = q_bf + (size_t)4194304;           // 8,388,608 u16
  unsigned short* w_bf = xT + (size_t)8388608;             //   131,072 u16
  unsigned short* kbuf = w_bf + (size_t)131072;            // 4,194,304 u16
  unsigned short* vpln = kbuf + (size_t)4194304;           // 10,321,920 u16

  haloattn_zero_border<<<2048, 256, 0, stream>>>(vpln);
  haloattn_cvt<<<dim3(64, 4, 8), 256, 0, stream>>>(x, q_w, kv_w, xT, w_bf);
  haloattn_proj_mfma<<<dim3(32, 2, 8), 512, 0, stream>>>(xT, w_bf, q_bf, kbuf, vpln);
  haloattn_attn_direct<<<4096, 64, 0, stream>>>(q_bf, kbuf, vpln,
                                                height_rel, width_rel, out);
}